// Round 11
// baseline (181.762 us; speedup 1.0000x reference)
//
#include <hip/hip_runtime.h>
#include <math.h>

#define BB 512
#define SS 16384
#define TPIF 6.28318530717958647692f

// float2 (b64) element pad. Measured "conflicts" are the structural b64 floor
// (4 lanes/bank-pair); layout already optimal -- do not re-tune.
#define PD(i) ((i) + ((i) >> 4) + ((i) >> 8))
#define NPD 17472   // PD(16383)=17469 < 17472; 139.8 KB of LDS
#define BBASE 8200  // 8K-IFFT region base; C natural occupies slots [0..8192]

// mixed-radix [8,8,8,8,4] storage map for the 16K forward DIF: frequency k
// lives at element s(k). R6 lesson: always wrap with PD().
__device__ __forceinline__ int sp(int k) {
    int s = ((k & 7) << 11) + (((k >> 3) & 7) << 8) + (((k >> 6) & 7) << 5)
          + (((k >> 9) & 7) << 2) + ((k >> 12) & 3);
    return PD(s);
}

// ---------------------------------------------------------------------------
// 64-VGPR design rule (R0-R10 evidence): allocator pins this kernel at 64
// VGPRs; keep <=~45 live everywhere. R11: one sincos per stage (p is
// c-invariant for Q<=1024; Q=2048's second butterfly = +sg/16-turn rotation)
// and shuffle-sourced Hann-conv neighbors in the unpack (consecutive lanes
// hold consecutive k).
// ---------------------------------------------------------------------------

// 16K radix-8 DIF stage (2 butterflies/thread), twiddle w^r on outputs.
// DOMI=true additionally bins raw element values into the MI histogram.
template <int SGN, int LOG2Q, bool DOMI = false>
__device__ __forceinline__ void stage_dif8(float2* sz, int t,
                                           float x0 = 0.f, float sbx = 0.f,
                                           float y0 = 0.f, float sby = 0.f,
                                           int* hsub = nullptr) {
    constexpr int Q = 1 << LOG2Q;
    constexpr int DQ = Q + (Q >> 4) + (Q >> 8);
    const float sg = (float)SGN;
    const float r2 = 0.70710678118654752f;
    // hoisted twiddle base: angle for c=0 butterfly (p0 = t & (Q-1));
    // for Q=2048 the c=1 butterfly is exactly +sg/16 turn away.
    float arev = sg * (float)(t & (Q - 1)) * (1.0f / (8.0f * (float)Q));
    float cb = __builtin_amdgcn_cosf(arev);
    float sb = __builtin_amdgcn_sinf(arev);
    #pragma unroll 1
    for (int c = 0; c < 2; ++c) {
        const int j = t + (c << 10);
        const int g = j >> LOG2Q;
        const int p = j & (Q - 1);
        const int i0 = PD((g << (LOG2Q + 3)) + p);
        int idx[8];
        #pragma unroll
        for (int k = 0; k < 8; ++k)
            idx[k] = (LOG2Q >= 4) ? (i0 + k * DQ) : (i0 + 4 * k + (k >> 2));  // Q=4 carry fix
        float2 z[8];
        #pragma unroll
        for (int k = 0; k < 8; ++k) z[k] = sz[idx[k]];
        if constexpr (DOMI) {   // bin raw values (first touch of each element)
            #pragma unroll
            for (int k = 0; k < 8; ++k) {
                int ix = (int)((z[k].x - x0) * sbx); ix = min(max(ix, 0), 9);
                int iy = (int)((z[k].y - y0) * sby); iy = min(max(iy, 0), 9);
                atomicAdd(&hsub[ix * 10 + iy], 1);
            }
        }
        float2 a0, a1, a2, a3, b0, b1, b2, b3;
        a0 = make_float2(z[0].x + z[4].x, z[0].y + z[4].y);
        b0 = make_float2(z[0].x - z[4].x, z[0].y - z[4].y);
        a1 = make_float2(z[1].x + z[5].x, z[1].y + z[5].y);
        b1 = make_float2(z[1].x - z[5].x, z[1].y - z[5].y);
        a2 = make_float2(z[2].x + z[6].x, z[2].y + z[6].y);
        b2 = make_float2(z[2].x - z[6].x, z[2].y - z[6].y);
        a3 = make_float2(z[3].x + z[7].x, z[3].y + z[7].y);
        b3 = make_float2(z[3].x - z[7].x, z[3].y - z[7].y);
        { float x = b1.x, y = b1.y; b1 = make_float2(r2 * (x - sg * y), r2 * (y + sg * x)); }
        { float x = b2.x, y = b2.y; b2 = make_float2(-sg * y, sg * x); }
        { float x = b3.x, y = b3.y; b3 = make_float2(-r2 * (x + sg * y), r2 * (sg * x - y)); }
        float2 o[8];
        {
            float t0r = a0.x + a2.x, t0i = a0.y + a2.y;
            float t1r = a0.x - a2.x, t1i = a0.y - a2.y;
            float t2r = a1.x + a3.x, t2i = a1.y + a3.y;
            float t3r = a1.x - a3.x, t3i = a1.y - a3.y;
            o[0] = make_float2(t0r + t2r, t0i + t2i);
            o[4] = make_float2(t0r - t2r, t0i - t2i);
            o[2] = make_float2(t1r - sg * t3i, t1i + sg * t3r);
            o[6] = make_float2(t1r + sg * t3i, t1i - sg * t3r);
        }
        {
            float t0r = b0.x + b2.x, t0i = b0.y + b2.y;
            float t1r = b0.x - b2.x, t1i = b0.y - b2.y;
            float t2r = b1.x + b3.x, t2i = b1.y + b3.y;
            float t3r = b1.x - b3.x, t3i = b1.y - b3.y;
            o[1] = make_float2(t0r + t2r, t0i + t2i);
            o[5] = make_float2(t0r - t2r, t0i - t2i);
            o[3] = make_float2(t1r - sg * t3i, t1i + sg * t3r);
            o[7] = make_float2(t1r + sg * t3i, t1i - sg * t3r);
        }
        sz[idx[0]] = o[0];
        float wr = cb, wi = sb;
        #pragma unroll
        for (int r = 1; r < 8; ++r) {
            sz[idx[r]] = make_float2(o[r].x * wr - o[r].y * wi,
                                     o[r].x * wi + o[r].y * wr);
            float nr = wr * cb - wi * sb, ni = wr * sb + wi * cb;
            wr = nr; wi = ni;
        }
        if constexpr (LOG2Q == 11) {   // advance base angle by sg/16 turn
            const float cs = 0.92387953251128674f;
            const float sn = 0.38268343236508977f * (float)SGN;
            float nb = cb * cs - sb * sn, nsb = cb * sn + sb * cs;
            cb = nb; sb = nsb;
        }
    }
    __syncthreads();
}

// 16K twiddle-free radix-4 stage on contiguous quads (Q=1, 4/thread)
template <int SGN>
__device__ __forceinline__ void stage_nt4(float2* sz, int t) {
    const float sg = (float)SGN;
    #pragma unroll 1
    for (int c = 0; c < 4; ++c) {
        const int j = t + (c << 10);
        const int i0 = 4 * j + (j >> 2) + (j >> 6);   // PD(4j); PD(4j+k)=i0+k
        float2 z0 = sz[i0], z1 = sz[i0 + 1], z2 = sz[i0 + 2], z3 = sz[i0 + 3];
        float t0r = z0.x + z2.x, t0i = z0.y + z2.y;
        float t1r = z0.x - z2.x, t1i = z0.y - z2.y;
        float t2r = z1.x + z3.x, t2i = z1.y + z3.y;
        float t3r = z1.x - z3.x, t3i = z1.y - z3.y;
        sz[i0]     = make_float2(t0r + t2r, t0i + t2i);
        sz[i0 + 2] = make_float2(t0r - t2r, t0i - t2i);
        sz[i0 + 1] = make_float2(t1r - sg * t3i, t1i + sg * t3r);
        sz[i0 + 3] = make_float2(t1r + sg * t3i, t1i - sg * t3r);
    }
    __syncthreads();
}

// ---------------------------------------------------------------------------
// 8K (half-size, real-output) inverse chain, region base bz = sz+BBASE.
// Chain: [fused B+r8 Q=1024], r8 Q=128, r8 Q=16, r4 Q=4, [fused r4 Q=1+argmax]
// Output map: time-lag n at slot (n&7)*1024 + ((n>>3)&7)*128 + ((n>>6)&7)*16
//             + ((n>>9)&3)*4 + (n>>11).
// PD increments: Q=1024 -> 1092 exact; Q=16 -> 17 exact; Q=128 -> 136k+(k>>1).
// ---------------------------------------------------------------------------
template <int SGN, int LOG2Q>
__device__ __forceinline__ void stage8k_dif8(float2* bz, int t) {
    constexpr int Q = 1 << LOG2Q;
    constexpr int DQ = Q + (Q >> 4) + (Q >> 8);
    constexpr int CORR = (LOG2Q == 7) ? 1 : 0;
    const float sg = (float)SGN;
    const float r2 = 0.70710678118654752f;
    const int g = t >> LOG2Q;                 // 1024 butterflies = 1/thread
    const int p = t & (Q - 1);
    const int i0 = PD((g << (LOG2Q + 3)) + p);
    int idx[8];
    #pragma unroll
    for (int k = 0; k < 8; ++k) idx[k] = i0 + k * DQ + CORR * (k >> 1);
    float2 z[8];
    #pragma unroll
    for (int k = 0; k < 8; ++k) z[k] = bz[idx[k]];
    float2 a0, a1, a2, a3, b0, b1, b2, b3;
    a0 = make_float2(z[0].x + z[4].x, z[0].y + z[4].y);
    b0 = make_float2(z[0].x - z[4].x, z[0].y - z[4].y);
    a1 = make_float2(z[1].x + z[5].x, z[1].y + z[5].y);
    b1 = make_float2(z[1].x - z[5].x, z[1].y - z[5].y);
    a2 = make_float2(z[2].x + z[6].x, z[2].y + z[6].y);
    b2 = make_float2(z[2].x - z[6].x, z[2].y - z[6].y);
    a3 = make_float2(z[3].x + z[7].x, z[3].y + z[7].y);
    b3 = make_float2(z[3].x - z[7].x, z[3].y - z[7].y);
    { float x = b1.x, y = b1.y; b1 = make_float2(r2 * (x - sg * y), r2 * (y + sg * x)); }
    { float x = b2.x, y = b2.y; b2 = make_float2(-sg * y, sg * x); }
    { float x = b3.x, y = b3.y; b3 = make_float2(-r2 * (x + sg * y), r2 * (sg * x - y)); }
    float2 o[8];
    {
        float t0r = a0.x + a2.x, t0i = a0.y + a2.y;
        float t1r = a0.x - a2.x, t1i = a0.y - a2.y;
        float t2r = a1.x + a3.x, t2i = a1.y + a3.y;
        float t3r = a1.x - a3.x, t3i = a1.y - a3.y;
        o[0] = make_float2(t0r + t2r, t0i + t2i);
        o[4] = make_float2(t0r - t2r, t0i - t2i);
        o[2] = make_float2(t1r - sg * t3i, t1i + sg * t3r);
        o[6] = make_float2(t1r + sg * t3i, t1i - sg * t3r);
    }
    {
        float t0r = b0.x + b2.x, t0i = b0.y + b2.y;
        float t1r = b0.x - b2.x, t1i = b0.y - b2.y;
        float t2r = b1.x + b3.x, t2i = b1.y + b3.y;
        float t3r = b1.x - b3.x, t3i = b1.y - b3.y;
        o[1] = make_float2(t0r + t2r, t0i + t2i);
        o[5] = make_float2(t0r - t2r, t0i - t2i);
        o[3] = make_float2(t1r - sg * t3i, t1i + sg * t3r);
        o[7] = make_float2(t1r + sg * t3i, t1i - sg * t3r);
    }
    const float arev = sg * (float)p * (1.0f / (8.0f * (float)Q));  // revolutions
    const float cb = __builtin_amdgcn_cosf(arev);
    const float sb = __builtin_amdgcn_sinf(arev);
    bz[idx[0]] = o[0];
    float wr = cb, wi = sb;
    #pragma unroll
    for (int r = 1; r < 8; ++r) {
        bz[idx[r]] = make_float2(o[r].x * wr - o[r].y * wi,
                                 o[r].x * wi + o[r].y * wr);
        float nr = wr * cb - wi * sb, ni = wr * sb + wi * cb;
        wr = nr; wi = ni;
    }
    __syncthreads();
}

// FUSED: build B[m] in registers from C (natural slots in sz) and run the
// first inverse stage (Q=1024, g=0, p=t) directly on it.
// B[m] = (C[m]+conj(C[M-m])) + i*W^m*(C[m]-conj(C[M-m])), W=e^{+2pi i/16384};
// thread t needs exactly B[t + 1024c], c=0..7 -- the values it builds.
__device__ __forceinline__ void inv_first(float2* sz, float2* bz, int t) {
    const float r2 = 0.70710678118654752f;
    float2 z[8];
    {
        float a0w = (float)t * (1.0f / 16384.0f);
        float wr = __builtin_amdgcn_cosf(a0w);
        float wi = __builtin_amdgcn_sinf(a0w);
        const float cs = 0.92387953251128674f;  // cos(2pi/16)
        const float sn = 0.38268343236508977f;  // sin(2pi/16)
        #pragma unroll
        for (int c = 0; c < 8; ++c) {
            int m = t + (c << 10);
            float2 cm = sz[m];
            float2 cn = sz[8192 - m];
            float Ax = cm.x + cn.x, Ay = cm.y - cn.y;
            float Dx = cm.x - cn.x, Dy = cm.y + cn.y;
            float WDx = Dx * wr - Dy * wi;
            float WDy = Dx * wi + Dy * wr;
            z[c] = make_float2(Ax - WDy, Ay + WDx);
            float nr = wr * cs - wi * sn, ni = wr * sn + wi * cs;
            wr = nr; wi = ni;
        }
    }
    // Q=1024 DIF butterfly, SGN=+1, i0=PD(t), stride 1092
    const float sg = 1.0f;
    const int i0 = PD(t);
    float2 a0, a1, a2, a3, b0, b1, b2, b3;
    a0 = make_float2(z[0].x + z[4].x, z[0].y + z[4].y);
    b0 = make_float2(z[0].x - z[4].x, z[0].y - z[4].y);
    a1 = make_float2(z[1].x + z[5].x, z[1].y + z[5].y);
    b1 = make_float2(z[1].x - z[5].x, z[1].y - z[5].y);
    a2 = make_float2(z[2].x + z[6].x, z[2].y + z[6].y);
    b2 = make_float2(z[2].x - z[6].x, z[2].y - z[6].y);
    a3 = make_float2(z[3].x + z[7].x, z[3].y + z[7].y);
    b3 = make_float2(z[3].x - z[7].x, z[3].y - z[7].y);
    { float x = b1.x, y = b1.y; b1 = make_float2(r2 * (x - sg * y), r2 * (y + sg * x)); }
    { float x = b2.x, y = b2.y; b2 = make_float2(-sg * y, sg * x); }
    { float x = b3.x, y = b3.y; b3 = make_float2(-r2 * (x + sg * y), r2 * (sg * x - y)); }
    float2 o[8];
    {
        float t0r = a0.x + a2.x, t0i = a0.y + a2.y;
        float t1r = a0.x - a2.x, t1i = a0.y - a2.y;
        float t2r = a1.x + a3.x, t2i = a1.y + a3.y;
        float t3r = a1.x - a3.x, t3i = a1.y - a3.y;
        o[0] = make_float2(t0r + t2r, t0i + t2i);
        o[4] = make_float2(t0r - t2r, t0i - t2i);
        o[2] = make_float2(t1r - sg * t3i, t1i + sg * t3r);
        o[6] = make_float2(t1r + sg * t3i, t1i - sg * t3r);
    }
    {
        float t0r = b0.x + b2.x, t0i = b0.y + b2.y;
        float t1r = b0.x - b2.x, t1i = b0.y - b2.y;
        float t2r = b1.x + b3.x, t2i = b1.y + b3.y;
        float t3r = b1.x - b3.x, t3i = b1.y - b3.y;
        o[1] = make_float2(t0r + t2r, t0i + t2i);
        o[5] = make_float2(t0r - t2r, t0i - t2i);
        o[3] = make_float2(t1r - sg * t3i, t1i + sg * t3r);
        o[7] = make_float2(t1r + sg * t3i, t1i - sg * t3r);
    }
    const float arev = (float)t * (1.0f / 8192.0f);  // +p/(8Q) revolutions
    const float cb = __builtin_amdgcn_cosf(arev);
    const float sb = __builtin_amdgcn_sinf(arev);
    bz[i0] = o[0];
    float wr = cb, wi = sb;
    #pragma unroll
    for (int r = 1; r < 8; ++r) {
        bz[i0 + r * 1092] = make_float2(o[r].x * wr - o[r].y * wi,
                                        o[r].x * wi + o[r].y * wr);
        float nr = wr * cb - wi * sb, ni = wr * sb + wi * cb;
        wr = nr; wi = ni;
    }
    __syncthreads();
}

// 8K radix-4 stage at Q=4 (2048 butterflies = 2/thread), twiddle w^r outputs
template <int SGN>
__device__ __forceinline__ void stage8k_dif4(float2* bz, int t) {
    const float sg = (float)SGN;
    // p = (t + 1024c) & 3 = t & 3 -- c-invariant; hoist the trig.
    const float a = sg * (float)(t & 3) * (1.0f / 16.0f);
    const float cb = __builtin_amdgcn_cosf(a);
    const float sb = __builtin_amdgcn_sinf(a);
    const float w2r = cb * cb - sb * sb, w2i = 2.0f * cb * sb;
    const float w3r = cb * w2r - sb * w2i, w3i = cb * w2i + sb * w2r;
    #pragma unroll 1
    for (int c = 0; c < 2; ++c) {
        const int j = t + (c << 10);
        const int g = j >> 2;
        const int p = j & 3;
        const int i0 = PD((g << 4) + p);      // PD(e0+4k) = PD(e0)+4k exactly
        float2 z0 = bz[i0], z1 = bz[i0 + 4], z2 = bz[i0 + 8], z3 = bz[i0 + 12];
        float t0r = z0.x + z2.x, t0i = z0.y + z2.y;
        float t1r = z0.x - z2.x, t1i = z0.y - z2.y;
        float t2r = z1.x + z3.x, t2i = z1.y + z3.y;
        float t3r = z1.x - z3.x, t3i = z1.y - z3.y;
        float b0r = t0r + t2r, b0i = t0i + t2i;
        float b2r = t0r - t2r, b2i = t0i - t2i;
        float b1r = t1r - sg * t3i, b1i = t1i + sg * t3r;
        float b3r = t1r + sg * t3i, b3i = t1i - sg * t3r;
        bz[i0]      = make_float2(b0r, b0i);
        bz[i0 + 4]  = make_float2(b1r * cb - b1i * sb,   b1r * sb + b1i * cb);
        bz[i0 + 8]  = make_float2(b2r * w2r - b2i * w2i, b2r * w2i + b2i * w2r);
        bz[i0 + 12] = make_float2(b3r * w3r - b3i * w3i, b3r * w3i + b3i * w3r);
    }
    __syncthreads();
}

// FUSED: last (Q=1, twiddle-free) radix-4 stage + argmax -- outputs are
// consumed in registers, never stored. Slot 4j+k' holds time index
// n = (j>>8) + 8*((j>>5)&7) + 64*((j>>2)&7) + 512*(j&3) + 2048*k';
// z.x = c[2n] (lag 2n), z.y = c[2n+1]. Tie-break: smallest lag.
__device__ __forceinline__ void inv_last_argmax(float2* bz, int t, float* pbv, int* pbi) {
    float bv = -3.4e38f; int bi = 0;
    #pragma unroll 1
    for (int c = 0; c < 2; ++c) {
        const int j = t + (c << 10);
        const int i0 = 4 * j + (j >> 2) + (j >> 6);
        float2 z0 = bz[i0], z1 = bz[i0 + 1], z2 = bz[i0 + 2], z3 = bz[i0 + 3];
        float t0r = z0.x + z2.x, t0i = z0.y + z2.y;
        float t1r = z0.x - z2.x, t1i = z0.y - z2.y;
        float t2r = z1.x + z3.x, t2i = z1.y + z3.y;
        float t3r = z1.x - z3.x, t3i = z1.y - z3.y;
        float re[4], im[4];
        re[0] = t0r + t2r; im[0] = t0i + t2i;   // k'=0
        re[1] = t1r - t3i; im[1] = t1i + t3r;   // k'=1 (sg=+1)
        re[2] = t0r - t2r; im[2] = t0i - t2i;   // k'=2
        re[3] = t1r + t3i; im[3] = t1i - t3r;   // k'=3
        const int nb = (j >> 8) + ((j >> 5) & 7) * 8 + ((j >> 2) & 7) * 64 + (j & 3) * 512;
        #pragma unroll
        for (int k = 0; k < 4; ++k) {
            int n2 = (nb + 2048 * k) << 1;
            if (re[k] > bv || (re[k] == bv && n2 < bi)) { bv = re[k]; bi = n2; }
            if (im[k] > bv || (im[k] == bv && n2 + 1 < bi)) { bv = im[k]; bi = n2 + 1; }
        }
    }
    *pbv = bv; *pbi = bi;
}

// ---------------------------------------------------------------------------
// Mega-kernel: one block per row: Pearson, MI (fused into FFT stage 1), ONE
// forward 16K FFT (shared by power spectrum AND phase correlation via the
// Hann spectral identity), then a HALF-SIZE (8K) real-output inverse FFT
// with fused endpoints.
// ---------------------------------------------------------------------------
__global__ __launch_bounds__(1024, 4) void k_main(const float* __restrict__ pred,
                                                  const float* __restrict__ targ,
                                                  const int* __restrict__ ip,
                                                  float* __restrict__ wpear,
                                                  float* __restrict__ wcos,
                                                  double* __restrict__ wnum,
                                                  double* __restrict__ wden,
                                                  float* __restrict__ wnmi) {
    __shared__ float2 sz[NPD];
    __shared__ double dpart[16 * 5];
    __shared__ float fpart[16 * 4];
    __shared__ int   subhist[1600];          // 16 per-warp sub-histograms
    __shared__ float hxm[10], hym[10];
    __shared__ float mterm[128];
    __shared__ float sbounds[4];             // x0, 10/(xmax-x0), y0, 10/(ymax-y0)
    __shared__ float svalw[16];
    __shared__ int   sidxw[16];

    const int row = blockIdx.x;
    const int t = threadIdx.x;
    const int w = t >> 6;
    const int lane = t & 63;
    float2* bz = &sz[BBASE];

    const float* xg = pred + (size_t)ip[0] * (size_t)BB * SS + (size_t)row * SS;
    const float* yg = targ + (size_t)row * SS;

    // ---- Load (float4) + Pearson sums (fp32 partials) + min/max, streaming
    //      into LDS (sz = x + i y == FFT1 input, natural order).
    {
        const float4* xg4 = reinterpret_cast<const float4*>(xg);
        const float4* yg4 = reinterpret_cast<const float4*>(yg);
        float sx = 0, sy = 0, sxy = 0, sxx = 0, syy = 0;
        float xmn = 3.4e38f, xmx = -3.4e38f, ymn = 3.4e38f, ymx = -3.4e38f;
        #pragma unroll
        for (int m2 = 0; m2 < 4; ++m2) {
            int idx = t + (m2 << 10);          // float4 index
            float4 a = xg4[idx];
            float4 b = yg4[idx];
            int n0 = idx << 2;
            sz[PD(n0 + 0)] = make_float2(a.x, b.x);
            sz[PD(n0 + 1)] = make_float2(a.y, b.y);
            sz[PD(n0 + 2)] = make_float2(a.z, b.z);
            sz[PD(n0 + 3)] = make_float2(a.w, b.w);
            float av[4] = {a.x, a.y, a.z, a.w};
            float bv[4] = {b.x, b.y, b.z, b.w};
            #pragma unroll
            for (int c = 0; c < 4; ++c) {
                float aa = av[c], bb = bv[c];
                sx += aa; sy += bb;
                sxy += aa * bb;
                sxx += aa * aa;
                syy += bb * bb;
                xmn = fminf(xmn, aa); xmx = fmaxf(xmx, aa);
                ymn = fminf(ymn, bb); ymx = fmaxf(ymx, bb);
            }
        }
        #pragma unroll
        for (int o = 32; o > 0; o >>= 1) {
            sx += __shfl_down(sx, o, 64);  sy += __shfl_down(sy, o, 64);
            sxy += __shfl_down(sxy, o, 64);
            sxx += __shfl_down(sxx, o, 64); syy += __shfl_down(syy, o, 64);
            xmn = fminf(xmn, __shfl_down(xmn, o, 64));
            xmx = fmaxf(xmx, __shfl_down(xmx, o, 64));
            ymn = fminf(ymn, __shfl_down(ymn, o, 64));
            ymx = fmaxf(ymx, __shfl_down(ymx, o, 64));
        }
        if (lane == 0) {
            dpart[w*5+0] = (double)sx; dpart[w*5+1] = (double)sy;
            dpart[w*5+2] = (double)sxy;
            dpart[w*5+3] = (double)sxx; dpart[w*5+4] = (double)syy;
            fpart[w*4+0] = xmn; fpart[w*4+1] = xmx; fpart[w*4+2] = ymn; fpart[w*4+3] = ymx;
        }
    }
    subhist[t] = 0;
    if (t < 576) subhist[1024 + t] = 0;
    __syncthreads();
    if (t == 0) {
        double v0=0,v1=0,v2=0,v3=0,v4=0;
        float b0=fpart[0], b1=fpart[1], b2=fpart[2], b3=fpart[3];
        for (int q = 0; q < 16; ++q) {
            v0 += dpart[q*5]; v1 += dpart[q*5+1]; v2 += dpart[q*5+2];
            v3 += dpart[q*5+3]; v4 += dpart[q*5+4];
            b0 = fminf(b0, fpart[q*4]);   b1 = fmaxf(b1, fpart[q*4+1]);
            b2 = fminf(b2, fpart[q*4+2]); b3 = fmaxf(b3, fpart[q*4+3]);
        }
        double N = (double)SS;
        double num = N * v2 - v0 * v1;
        double den = sqrt((N * v3 - v0 * v0) * (N * v4 - v1 * v1));
        wpear[row] = (float)(1.0 - num / den);
        sbounds[0] = b0; sbounds[1] = 10.0f / (b1 - b0);
        sbounds[2] = b2; sbounds[3] = 10.0f / (b3 - b2);
    }
    __syncthreads();

    // ---- FFT1 stage 1 (Q=2048) with FUSED MI binning (reads every element
    //      exactly once, pre-butterfly values are the raw x,y).
    {
        const float x0 = sbounds[0], sbx = sbounds[1];
        const float y0 = sbounds[2], sby = sbounds[3];
        int* hsub = subhist + w * 100;       // one sub-hist per warp
        stage_dif8<-1, 11, true>(sz, t, x0, sbx, y0, sby, hsub);
    }

    // ---- MI finalize (subhist complete after stage-1 barrier)
    if (t < 100) {
        int s = 0;
        #pragma unroll
        for (int q = 0; q < 16; ++q) s += subhist[t + 100 * q];
        subhist[t] = s;
    }
    __syncthreads();
    if (t < 10) {
        int s1 = 0, s2 = 0;
        for (int j = 0; j < 10; ++j) { s1 += subhist[t*10+j]; s2 += subhist[j*10+t]; }
        hxm[t] = (float)s1; hym[t] = (float)s2;
    }
    __syncthreads();
    {
        float term = 0.0f;
        if (t < 100) {
            const float denom = 8388608.0f, eps = 1e-8f;
            float pxy = (float)subhist[t] / denom;
            float px = hxm[t / 10] / denom, py = hym[t % 10] / denom;
            term = pxy * logf((pxy + eps) / (px * py + eps));
        }
        if (t < 128) mterm[t] = (t < 100) ? term : 0.0f;
    }
    __syncthreads();
    if (t == 0) {
        const float denom = 8388608.0f, eps = 1e-8f;
        float mi = 0.0f;
        for (int q = 0; q < 100; ++q) mi += mterm[q];
        float hxe = 0.0f, hye = 0.0f;
        for (int q = 0; q < 10; ++q) {
            float px = hxm[q] / denom, py = hym[q] / denom;
            hxe -= px * logf(px + eps);
            hye -= py * logf(py + eps);
        }
        wnmi[row] = mi / (0.5f * (hxe + hye));
    }
    // no barrier needed: stage 2 below ends with one; t==0 just arrives late

    // ---- FFT1 remaining forward stages: natural -> s-order
    stage_dif8<-1,  8>(sz, t);   // Q=256
    stage_dif8<-1,  5>(sz, t);   // Q=32
    stage_dif8<-1,  2>(sz, t);   // Q=4
    stage_nt4<-1>(sz, t);        // Q=1, twiddle-free

    // ---- Fused unpack: power sums (unwindowed) + phase-correlation C from
    //      the Hann-convolved spectrum (Zw[k] = 0.5Z[k]-0.25(Z[k-1]+Z[k+1]),
    //      exact for the periodic window). Z[k+-1] come from NEIGHBOR LANES
    //      (consecutive lanes hold consecutive k; km mirrors k so Z[km-+1]
    //      is the same neighbor's zb). Lanes 0/63 patch via direct reads.
    //      Reads before barrier; C written to NATURAL slots [0..8192] after.
    {
        double anum = 0.0, aden = 0.0;
        float crv[8], civ[8];
        #pragma unroll 1
        for (int m = 0; m < 8; ++m) {
            int k = t + (m << 10);
            int km = (SS - k) & (SS - 1);
            float2 za = sz[sp(k)];
            float2 zb = sz[sp(km)];
            float ar  = za.x, ai  = za.y;
            float cr0 = zb.x, ci0 = zb.y;
            float xr = 0.5f * (ar + cr0), xi = 0.5f * (ai - ci0);
            float yr = 0.5f * (ai + ci0), yi = 0.5f * (cr0 - ar);
            float xp = xr * xr + xi * xi;
            float tp = yr * yr + yi * yi;
            anum += (double)fabsf(xp - tp);
            aden += (double)tp;
            // neighbors via wave shuffles
            float2 zap, zam, zbp, zbm;
            zap.x = __shfl_down(za.x, 1, 64); zap.y = __shfl_down(za.y, 1, 64);
            zam.x = __shfl_up(za.x, 1, 64);   zam.y = __shfl_up(za.y, 1, 64);
            zbm.x = __shfl_down(zb.x, 1, 64); zbm.y = __shfl_down(zb.y, 1, 64);
            zbp.x = __shfl_up(zb.x, 1, 64);   zbp.y = __shfl_up(zb.y, 1, 64);
            if (lane == 63) {
                zap = sz[sp((k + 1) & (SS - 1))];
                zbm = sz[sp((km - 1) & (SS - 1))];
            }
            if (lane == 0) {
                zam = sz[sp((k - 1) & (SS - 1))];
                zbp = sz[sp((km + 1) & (SS - 1))];
            }
            float zwr = 0.5f * ar  - 0.25f * (zap.x + zam.x);
            float zwi = 0.5f * ai  - 0.25f * (zap.y + zam.y);
            float vwr = 0.5f * cr0 - 0.25f * (zbp.x + zbm.x);
            float vwi = 0.5f * ci0 - 0.25f * (zbp.y + zbm.y);
            float xwr = 0.5f * (zwr + vwr), xwi = 0.5f * (zwi - vwi);
            float ywr = 0.5f * (zwi + vwi), ywi = 0.5f * (vwr - zwr);
            float cr = xwr * ywr + xwi * ywi;
            float ci = xwi * ywr - xwr * ywi;
            float mag = sqrtf(cr * cr + ci * ci);
            crv[m] = cr / mag; civ[m] = ci / mag;
        }
        float c8 = 0.0f;
        if (t == 0) {   // k = 8192 (self-conjugate)
            float2 z0 = sz[sp(8192)];
            float2 zp = sz[sp(8193)];
            float2 zm = sz[sp(8191)];
            float ar = z0.x, ai = z0.y;
            anum += (double)fabsf(ar * ar - ai * ai);
            aden += (double)(ai * ai);
            float zwr = 0.5f * ar - 0.25f * (zp.x + zm.x);
            float zwi = 0.5f * ai - 0.25f * (zp.y + zm.y);
            float pr = zwr * zwi;          // Xw real, Yw real at Nyquist
            c8 = pr / fabsf(pr);
        }
        #pragma unroll
        for (int o = 32; o > 0; o >>= 1) {
            anum += __shfl_down(anum, o, 64);
            aden += __shfl_down(aden, o, 64);
        }
        if (lane == 0) { dpart[w*2] = anum; dpart[w*2+1] = aden; }
        __syncthreads();   // all spectrum reads done; safe to overwrite
        #pragma unroll
        for (int m = 0; m < 8; ++m) {
            int k = t + (m << 10);
            sz[k] = make_float2(crv[m], civ[m]);   // C natural, k in [0,8192)
        }
        if (t == 0) {
            sz[8192] = make_float2(c8, 0.0f);
            double a = 0, b = 0;
            for (int q2_ = 0; q2_ < 16; ++q2_) { a += dpart[q2_*2]; b += dpart[q2_*2+1]; }
            wnum[row] = a; wden[row] = b;
        }
    }
    __syncthreads();

    // ---- 8K inverse: fused B-build+first stage, middle stages, fused last
    inv_first(sz, bz, t);         // B in regs + Q=1024 (barrier inside)
    stage8k_dif8<1,  7>(bz, t);   // Q=128
    stage8k_dif8<1,  4>(bz, t);   // Q=16
    stage8k_dif4<1>(bz, t);       // Q=4
    {
        float bv; int bi;
        inv_last_argmax(bz, t, &bv, &bi);   // Q=1 butterfly + argmax, no store
        #pragma unroll
        for (int o = 32; o > 0; o >>= 1) {
            float v2 = __shfl_down(bv, o, 64);
            int i2 = __shfl_down(bi, o, 64);
            if (v2 > bv || (v2 == bv && i2 < bi)) { bv = v2; bi = i2; }
        }
        if (lane == 0) { svalw[w] = bv; sidxw[w] = bi; }
    }
    __syncthreads();
    if (t == 0) {
        float bv = svalw[0]; int bi = sidxw[0];
        for (int q = 1; q < 16; ++q) {
            if (svalw[q] > bv || (svalw[q] == bv && sidxw[q] < bi)) { bv = svalw[q]; bi = sidxw[q]; }
        }
        wcos[row] = cosf(TPIF * (float)bi / 16384.0f);
    }
}

// ---------------------------------------------------------------------------
// Final combine (reads epoch on-device; graph-safe). Wave-shuffle reductions.
// ---------------------------------------------------------------------------
__global__ __launch_bounds__(512) void k_combine(const float* __restrict__ wpear,
                                                 const float* __restrict__ wcos,
                                                 const double* __restrict__ wnum,
                                                 const double* __restrict__ wden,
                                                 const float* __restrict__ wnmi,
                                                 const int* __restrict__ ep,
                                                 float* __restrict__ out) {
    __shared__ double dp[8 * 5];
    const int tid = threadIdx.x;
    const int w = tid >> 6, lane = tid & 63;
    double v0 = (double)wpear[tid], v1 = (double)wcos[tid];
    double v2 = wnum[tid], v3 = wden[tid], v4 = (double)wnmi[tid];
    #pragma unroll
    for (int o = 32; o > 0; o >>= 1) {
        v0 += __shfl_down(v0, o, 64); v1 += __shfl_down(v1, o, 64);
        v2 += __shfl_down(v2, o, 64); v3 += __shfl_down(v3, o, 64);
        v4 += __shfl_down(v4, o, 64);
    }
    if (lane == 0) {
        dp[w*5+0] = v0; dp[w*5+1] = v1; dp[w*5+2] = v2; dp[w*5+3] = v3; dp[w*5+4] = v4;
    }
    __syncthreads();
    if (tid == 0) {
        double s0=0,s1=0,s2=0,s3=0,s4=0;
        for (int q = 0; q < 8; ++q) {
            s0 += dp[q*5]; s1 += dp[q*5+1]; s2 += dp[q*5+2]; s3 += dp[q*5+3]; s4 += dp[q*5+4];
        }
        int epoch = ep[0];
        double loss = s0 / 512.0;
        if (epoch >= 400) {
            loss += 1.0 - s1 / 512.0;
            loss += s2 / s3;
        }
        if (epoch >= 700) {
            loss += 1.0 - s4 / 512.0;
        }
        out[0] = (float)loss;
    }
}

// ---------------------------------------------------------------------------
extern "C" void kernel_launch(void* const* d_in, const int* in_sizes, int n_in,
                              void* d_out, int out_size, void* d_ws, size_t ws_size,
                              hipStream_t stream) {
    const float* pred = (const float*)d_in[0];   // [2, 512, 16384] f32
    const float* targ = (const float*)d_in[1];   // [512, 16384] f32
    const int* ip = (const int*)d_in[2];         // scalar i
    const int* ep = (const int*)d_in[3];         // scalar epoch
    float* out = (float*)d_out;

    double* wnum = (double*)d_ws;                // [512]
    double* wden = wnum + BB;                    // [512]
    float* wpear = (float*)(wden + BB);          // [512]
    float* wcos = wpear + BB;                    // [512]
    float* wnmi = wcos + BB;                     // [512]

    k_main<<<dim3(BB), dim3(1024), 0, stream>>>(pred, targ, ip, wpear, wcos, wnum, wden, wnmi);
    k_combine<<<dim3(1), dim3(512), 0, stream>>>(wpear, wcos, wnum, wden, wnmi, ep, out);
}

// Round 12
// 176.068 us; speedup vs baseline: 1.0323x; 1.0323x over previous
//
#include <hip/hip_runtime.h>
#include <math.h>

#define BB 512
#define SS 16384
#define TPIF 6.28318530717958647692f

// float2 (b64) element pad. Measured "conflicts" are the structural b64 floor
// (4 lanes/bank-pair); layout already optimal -- do not re-tune.
#define PD(i) ((i) + ((i) >> 4) + ((i) >> 8))
#define NPD 17472   // PD(16383)=17469 < 17472; 139.8 KB of LDS
#define BBASE 8200  // 8K-IFFT region base; C natural occupies slots [0..8192]

// mixed-radix [8,8,8,8,4] storage map for the 16K forward DIF: frequency k
// lives at element s(k). R6 lesson: always wrap with PD().
__device__ __forceinline__ int sp(int k) {
    int s = ((k & 7) << 11) + (((k >> 3) & 7) << 8) + (((k >> 6) & 7) << 5)
          + (((k >> 9) & 7) << 2) + ((k >> 12) & 3);
    return PD(s);
}

// ---------------------------------------------------------------------------
// 64-VGPR design rule (R0-R11 evidence). R12: latency attack -- prefetch both
// butterflies' loads in forward r8 stages (peak live ~55-60, tripwire:
// WRITE_SIZE); piggyback MI-finalize barriers on FFT stage barriers.
// ---------------------------------------------------------------------------

// radix-8 DIF butterfly + twiddled store (z held in registers by caller).
template <int SGN, int LOG2Q>
__device__ __forceinline__ void bfly8_store(float2* sz, const float2* z, int i0,
                                            float cb, float sb) {
    constexpr int Q = 1 << LOG2Q;
    constexpr int DQ = Q + (Q >> 4) + (Q >> 8);
    const float sg = (float)SGN;
    const float r2 = 0.70710678118654752f;
    float2 a0, a1, a2, a3, b0, b1, b2, b3;
    a0 = make_float2(z[0].x + z[4].x, z[0].y + z[4].y);
    b0 = make_float2(z[0].x - z[4].x, z[0].y - z[4].y);
    a1 = make_float2(z[1].x + z[5].x, z[1].y + z[5].y);
    b1 = make_float2(z[1].x - z[5].x, z[1].y - z[5].y);
    a2 = make_float2(z[2].x + z[6].x, z[2].y + z[6].y);
    b2 = make_float2(z[2].x - z[6].x, z[2].y - z[6].y);
    a3 = make_float2(z[3].x + z[7].x, z[3].y + z[7].y);
    b3 = make_float2(z[3].x - z[7].x, z[3].y - z[7].y);
    { float x = b1.x, y = b1.y; b1 = make_float2(r2 * (x - sg * y), r2 * (y + sg * x)); }
    { float x = b2.x, y = b2.y; b2 = make_float2(-sg * y, sg * x); }
    { float x = b3.x, y = b3.y; b3 = make_float2(-r2 * (x + sg * y), r2 * (sg * x - y)); }
    float2 o[8];
    {
        float t0r = a0.x + a2.x, t0i = a0.y + a2.y;
        float t1r = a0.x - a2.x, t1i = a0.y - a2.y;
        float t2r = a1.x + a3.x, t2i = a1.y + a3.y;
        float t3r = a1.x - a3.x, t3i = a1.y - a3.y;
        o[0] = make_float2(t0r + t2r, t0i + t2i);
        o[4] = make_float2(t0r - t2r, t0i - t2i);
        o[2] = make_float2(t1r - sg * t3i, t1i + sg * t3r);
        o[6] = make_float2(t1r + sg * t3i, t1i - sg * t3r);
    }
    {
        float t0r = b0.x + b2.x, t0i = b0.y + b2.y;
        float t1r = b0.x - b2.x, t1i = b0.y - b2.y;
        float t2r = b1.x + b3.x, t2i = b1.y + b3.y;
        float t3r = b1.x - b3.x, t3i = b1.y - b3.y;
        o[1] = make_float2(t0r + t2r, t0i + t2i);
        o[5] = make_float2(t0r - t2r, t0i - t2i);
        o[3] = make_float2(t1r - sg * t3i, t1i + sg * t3r);
        o[7] = make_float2(t1r + sg * t3i, t1i - sg * t3r);
    }
    sz[(LOG2Q >= 4) ? i0 : i0] = o[0];
    float wr = cb, wi = sb;
    #pragma unroll
    for (int r = 1; r < 8; ++r) {
        const int ir = (LOG2Q >= 4) ? (i0 + r * DQ) : (i0 + 4 * r + (r >> 2));
        sz[ir] = make_float2(o[r].x * wr - o[r].y * wi,
                             o[r].x * wi + o[r].y * wr);
        float nr = wr * cb - wi * sb, ni = wr * sb + wi * cb;
        wr = nr; wi = ni;
    }
}

// 16K forward radix-8 stage (Q<=1024): PREFETCH both butterflies' 16 loads,
// then butterfly+store each. p is c-invariant (1024 % Q == 0) -> one sincos.
template <int SGN, int LOG2Q>
__device__ __forceinline__ void stage_dif8(float2* sz, int t) {
    constexpr int Q = 1 << LOG2Q;
    constexpr int DQ = Q + (Q >> 4) + (Q >> 8);
    const int gA = t >> LOG2Q;
    const int p  = t & (Q - 1);
    const int i0A = PD((gA << (LOG2Q + 3)) + p);
    const int gB = (t + 1024) >> LOG2Q;
    const int i0B = PD((gB << (LOG2Q + 3)) + p);
    float2 zA[8], zB[8];
    #pragma unroll
    for (int k = 0; k < 8; ++k)
        zA[k] = sz[(LOG2Q >= 4) ? (i0A + k * DQ) : (i0A + 4 * k + (k >> 2))];
    #pragma unroll
    for (int k = 0; k < 8; ++k)
        zB[k] = sz[(LOG2Q >= 4) ? (i0B + k * DQ) : (i0B + 4 * k + (k >> 2))];
    const float arev = (float)SGN * (float)p * (1.0f / (8.0f * (float)Q));
    const float cb = __builtin_amdgcn_cosf(arev);
    const float sb = __builtin_amdgcn_sinf(arev);
    bfly8_store<SGN, LOG2Q>(sz, zA, i0A, cb, sb);
    bfly8_store<SGN, LOG2Q>(sz, zB, i0B, cb, sb);
    __syncthreads();
}

// MI-fused first forward stage (Q=2048, SGN=-1): 2 butterflies unroll-1
// (atomic pressure), twiddle base advanced by -1/16 turn between them.
__device__ __forceinline__ void stage1_mi(float2* sz, int t, float x0, float sbx,
                                          float y0, float sby, int* hsub) {
    constexpr int LOG2Q = 11;
    constexpr int Q = 1 << LOG2Q;
    constexpr int DQ = Q + (Q >> 4) + (Q >> 8);
    const float sg = -1.0f;
    const float r2 = 0.70710678118654752f;
    float arev = sg * (float)(t & (Q - 1)) * (1.0f / (8.0f * (float)Q));
    float cb = __builtin_amdgcn_cosf(arev);
    float sb = __builtin_amdgcn_sinf(arev);
    #pragma unroll 1
    for (int c = 0; c < 2; ++c) {
        const int j = t + (c << 10);
        const int g = j >> LOG2Q;
        const int p = j & (Q - 1);
        const int i0 = PD((g << (LOG2Q + 3)) + p);
        float2 z[8];
        #pragma unroll
        for (int k = 0; k < 8; ++k) z[k] = sz[i0 + k * DQ];
        #pragma unroll
        for (int k = 0; k < 8; ++k) {
            int ix = (int)((z[k].x - x0) * sbx); ix = min(max(ix, 0), 9);
            int iy = (int)((z[k].y - y0) * sby); iy = min(max(iy, 0), 9);
            atomicAdd(&hsub[ix * 10 + iy], 1);
        }
        bfly8_store<-1, LOG2Q>(sz, z, i0, cb, sb);
        // advance base angle by -1/16 turn for the c=1 butterfly
        const float cs = 0.92387953251128674f;
        const float sn = -0.38268343236508977f;
        float nb = cb * cs - sb * sn, nsb = cb * sn + sb * cs;
        cb = nb; sb = nsb;
    }
    __syncthreads();
}

// 16K twiddle-free radix-4 stage on contiguous quads (Q=1, 4/thread), full
// unroll so loads pipeline ahead of compute.
template <int SGN>
__device__ __forceinline__ void stage_nt4(float2* sz, int t) {
    const float sg = (float)SGN;
    #pragma unroll
    for (int c = 0; c < 4; ++c) {
        const int j = t + (c << 10);
        const int i0 = 4 * j + (j >> 2) + (j >> 6);   // PD(4j); PD(4j+k)=i0+k
        float2 z0 = sz[i0], z1 = sz[i0 + 1], z2 = sz[i0 + 2], z3 = sz[i0 + 3];
        float t0r = z0.x + z2.x, t0i = z0.y + z2.y;
        float t1r = z0.x - z2.x, t1i = z0.y - z2.y;
        float t2r = z1.x + z3.x, t2i = z1.y + z3.y;
        float t3r = z1.x - z3.x, t3i = z1.y - z3.y;
        sz[i0]     = make_float2(t0r + t2r, t0i + t2i);
        sz[i0 + 2] = make_float2(t0r - t2r, t0i - t2i);
        sz[i0 + 1] = make_float2(t1r - sg * t3i, t1i + sg * t3r);
        sz[i0 + 3] = make_float2(t1r + sg * t3i, t1i - sg * t3r);
    }
    __syncthreads();
}

// ---------------------------------------------------------------------------
// 8K (half-size, real-output) inverse chain, region base bz = sz+BBASE.
// Chain: [fused B+r8 Q=1024], r8 Q=128, r8 Q=16, r4 Q=4, [fused r4 Q=1+argmax]
// Output map: time-lag n at slot (n&7)*1024 + ((n>>3)&7)*128 + ((n>>6)&7)*16
//             + ((n>>9)&3)*4 + (n>>11).
// PD increments: Q=1024 -> 1092 exact; Q=16 -> 17 exact; Q=128 -> 136k+(k>>1).
// ---------------------------------------------------------------------------
template <int SGN, int LOG2Q>
__device__ __forceinline__ void stage8k_dif8(float2* bz, int t) {
    constexpr int Q = 1 << LOG2Q;
    constexpr int DQ = Q + (Q >> 4) + (Q >> 8);
    constexpr int CORR = (LOG2Q == 7) ? 1 : 0;
    const float sg = (float)SGN;
    const int g = t >> LOG2Q;                 // 1024 butterflies = 1/thread
    const int p = t & (Q - 1);
    const int i0 = PD((g << (LOG2Q + 3)) + p);
    int idx[8];
    #pragma unroll
    for (int k = 0; k < 8; ++k) idx[k] = i0 + k * DQ + CORR * (k >> 1);
    float2 z[8];
    #pragma unroll
    for (int k = 0; k < 8; ++k) z[k] = bz[idx[k]];
    const float arev = sg * (float)p * (1.0f / (8.0f * (float)Q));
    const float cb = __builtin_amdgcn_cosf(arev);
    const float sb = __builtin_amdgcn_sinf(arev);
    // butterfly + store (idx pattern differs from 16K only via CORR; inline)
    const float r2 = 0.70710678118654752f;
    float2 a0, a1, a2, a3, b0, b1, b2, b3;
    a0 = make_float2(z[0].x + z[4].x, z[0].y + z[4].y);
    b0 = make_float2(z[0].x - z[4].x, z[0].y - z[4].y);
    a1 = make_float2(z[1].x + z[5].x, z[1].y + z[5].y);
    b1 = make_float2(z[1].x - z[5].x, z[1].y - z[5].y);
    a2 = make_float2(z[2].x + z[6].x, z[2].y + z[6].y);
    b2 = make_float2(z[2].x - z[6].x, z[2].y - z[6].y);
    a3 = make_float2(z[3].x + z[7].x, z[3].y + z[7].y);
    b3 = make_float2(z[3].x - z[7].x, z[3].y - z[7].y);
    { float x = b1.x, y = b1.y; b1 = make_float2(r2 * (x - sg * y), r2 * (y + sg * x)); }
    { float x = b2.x, y = b2.y; b2 = make_float2(-sg * y, sg * x); }
    { float x = b3.x, y = b3.y; b3 = make_float2(-r2 * (x + sg * y), r2 * (sg * x - y)); }
    float2 o[8];
    {
        float t0r = a0.x + a2.x, t0i = a0.y + a2.y;
        float t1r = a0.x - a2.x, t1i = a0.y - a2.y;
        float t2r = a1.x + a3.x, t2i = a1.y + a3.y;
        float t3r = a1.x - a3.x, t3i = a1.y - a3.y;
        o[0] = make_float2(t0r + t2r, t0i + t2i);
        o[4] = make_float2(t0r - t2r, t0i - t2i);
        o[2] = make_float2(t1r - sg * t3i, t1i + sg * t3r);
        o[6] = make_float2(t1r + sg * t3i, t1i - sg * t3r);
    }
    {
        float t0r = b0.x + b2.x, t0i = b0.y + b2.y;
        float t1r = b0.x - b2.x, t1i = b0.y - b2.y;
        float t2r = b1.x + b3.x, t2i = b1.y + b3.y;
        float t3r = b1.x - b3.x, t3i = b1.y - b3.y;
        o[1] = make_float2(t0r + t2r, t0i + t2i);
        o[5] = make_float2(t0r - t2r, t0i - t2i);
        o[3] = make_float2(t1r - sg * t3i, t1i + sg * t3r);
        o[7] = make_float2(t1r + sg * t3i, t1i - sg * t3r);
    }
    bz[idx[0]] = o[0];
    float wr = cb, wi = sb;
    #pragma unroll
    for (int r = 1; r < 8; ++r) {
        bz[idx[r]] = make_float2(o[r].x * wr - o[r].y * wi,
                                 o[r].x * wi + o[r].y * wr);
        float nr = wr * cb - wi * sb, ni = wr * sb + wi * cb;
        wr = nr; wi = ni;
    }
    __syncthreads();
}

// FUSED: build B[m] in registers from C (natural slots in sz) and run the
// first inverse stage (Q=1024, g=0, p=t) directly on it.
// B[m] = (C[m]+conj(C[M-m])) + i*W^m*(C[m]-conj(C[M-m])), W=e^{+2pi i/16384};
// thread t needs exactly B[t + 1024c], c=0..7 -- the values it builds.
__device__ __forceinline__ void inv_first(float2* sz, float2* bz, int t) {
    float2 z[8];
    {
        float a0w = (float)t * (1.0f / 16384.0f);
        float wr = __builtin_amdgcn_cosf(a0w);
        float wi = __builtin_amdgcn_sinf(a0w);
        const float cs = 0.92387953251128674f;  // cos(2pi/16)
        const float sn = 0.38268343236508977f;  // sin(2pi/16)
        #pragma unroll
        for (int c = 0; c < 8; ++c) {
            int m = t + (c << 10);
            float2 cm = sz[m];
            float2 cn = sz[8192 - m];
            float Ax = cm.x + cn.x, Ay = cm.y - cn.y;
            float Dx = cm.x - cn.x, Dy = cm.y + cn.y;
            float WDx = Dx * wr - Dy * wi;
            float WDy = Dx * wi + Dy * wr;
            z[c] = make_float2(Ax - WDy, Ay + WDx);
            float nr = wr * cs - wi * sn, ni = wr * sn + wi * cs;
            wr = nr; wi = ni;
        }
    }
    // Q=1024 DIF butterfly, SGN=+1, i0=PD(t), stride 1092 (LOG2Q=10 path)
    const float arev = (float)t * (1.0f / 8192.0f);
    const float cb = __builtin_amdgcn_cosf(arev);
    const float sb = __builtin_amdgcn_sinf(arev);
    bfly8_store<1, 10>(bz, z, PD(t), cb, sb);
    __syncthreads();
}

// 8K radix-4 stage at Q=4 (2048 butterflies = 2/thread), hoisted trig,
// full unroll so both butterflies' loads pipeline.
template <int SGN>
__device__ __forceinline__ void stage8k_dif4(float2* bz, int t) {
    const float sg = (float)SGN;
    const float a = sg * (float)(t & 3) * (1.0f / 16.0f);
    const float cb = __builtin_amdgcn_cosf(a);
    const float sb = __builtin_amdgcn_sinf(a);
    const float w2r = cb * cb - sb * sb, w2i = 2.0f * cb * sb;
    const float w3r = cb * w2r - sb * w2i, w3i = cb * w2i + sb * w2r;
    #pragma unroll
    for (int c = 0; c < 2; ++c) {
        const int j = t + (c << 10);
        const int g = j >> 2;
        const int p = j & 3;
        const int i0 = PD((g << 4) + p);      // PD(e0+4k) = PD(e0)+4k exactly
        float2 z0 = bz[i0], z1 = bz[i0 + 4], z2 = bz[i0 + 8], z3 = bz[i0 + 12];
        float t0r = z0.x + z2.x, t0i = z0.y + z2.y;
        float t1r = z0.x - z2.x, t1i = z0.y - z2.y;
        float t2r = z1.x + z3.x, t2i = z1.y + z3.y;
        float t3r = z1.x - z3.x, t3i = z1.y - z3.y;
        float b0r = t0r + t2r, b0i = t0i + t2i;
        float b2r = t0r - t2r, b2i = t0i - t2i;
        float b1r = t1r - sg * t3i, b1i = t1i + sg * t3r;
        float b3r = t1r + sg * t3i, b3i = t1i - sg * t3r;
        bz[i0]      = make_float2(b0r, b0i);
        bz[i0 + 4]  = make_float2(b1r * cb - b1i * sb,   b1r * sb + b1i * cb);
        bz[i0 + 8]  = make_float2(b2r * w2r - b2i * w2i, b2r * w2i + b2i * w2r);
        bz[i0 + 12] = make_float2(b3r * w3r - b3i * w3i, b3r * w3i + b3i * w3r);
    }
    __syncthreads();
}

// FUSED: last (Q=1, twiddle-free) radix-4 stage + argmax -- outputs are
// consumed in registers, never stored. Slot 4j+k' holds time index
// n = (j>>8) + 8*((j>>5)&7) + 64*((j>>2)&7) + 512*(j&3) + 2048*k';
// z.x = c[2n] (lag 2n), z.y = c[2n+1]. Tie-break: smallest lag.
__device__ __forceinline__ void inv_last_argmax(float2* bz, int t, float* pbv, int* pbi) {
    float bv = -3.4e38f; int bi = 0;
    #pragma unroll
    for (int c = 0; c < 2; ++c) {
        const int j = t + (c << 10);
        const int i0 = 4 * j + (j >> 2) + (j >> 6);
        float2 z0 = bz[i0], z1 = bz[i0 + 1], z2 = bz[i0 + 2], z3 = bz[i0 + 3];
        float t0r = z0.x + z2.x, t0i = z0.y + z2.y;
        float t1r = z0.x - z2.x, t1i = z0.y - z2.y;
        float t2r = z1.x + z3.x, t2i = z1.y + z3.y;
        float t3r = z1.x - z3.x, t3i = z1.y - z3.y;
        float re[4], im[4];
        re[0] = t0r + t2r; im[0] = t0i + t2i;   // k'=0
        re[1] = t1r - t3i; im[1] = t1i + t3r;   // k'=1 (sg=+1)
        re[2] = t0r - t2r; im[2] = t0i - t2i;   // k'=2
        re[3] = t1r + t3i; im[3] = t1i - t3r;   // k'=3
        const int nb = (j >> 8) + ((j >> 5) & 7) * 8 + ((j >> 2) & 7) * 64 + (j & 3) * 512;
        #pragma unroll
        for (int k = 0; k < 4; ++k) {
            int n2 = (nb + 2048 * k) << 1;
            if (re[k] > bv || (re[k] == bv && n2 < bi)) { bv = re[k]; bi = n2; }
            if (im[k] > bv || (im[k] == bv && n2 + 1 < bi)) { bv = im[k]; bi = n2 + 1; }
        }
    }
    *pbv = bv; *pbi = bi;
}

// ---------------------------------------------------------------------------
// Mega-kernel: one block per row: Pearson, MI (binning fused into FFT stage 1,
// finalize piggybacked on stage barriers), ONE forward 16K FFT (shared by
// power spectrum AND phase correlation via the Hann spectral identity), then
// a HALF-SIZE (8K) real-output inverse FFT with fused endpoints.
// ---------------------------------------------------------------------------
__global__ __launch_bounds__(1024, 4) void k_main(const float* __restrict__ pred,
                                                  const float* __restrict__ targ,
                                                  const int* __restrict__ ip,
                                                  float* __restrict__ wpear,
                                                  float* __restrict__ wcos,
                                                  double* __restrict__ wnum,
                                                  double* __restrict__ wden,
                                                  float* __restrict__ wnmi) {
    __shared__ float2 sz[NPD];
    __shared__ double dpart[16 * 5];
    __shared__ float fpart[16 * 4];
    __shared__ int   subhist[1600];          // 16 per-warp sub-histograms
    __shared__ float hxm[10], hym[10];
    __shared__ float mterm[128];
    __shared__ float sbounds[4];             // x0, 10/(xmax-x0), y0, 10/(ymax-y0)
    __shared__ float svalw[16];
    __shared__ int   sidxw[16];

    const int row = blockIdx.x;
    const int t = threadIdx.x;
    const int w = t >> 6;
    const int lane = t & 63;
    float2* bz = &sz[BBASE];

    const float* xg = pred + (size_t)ip[0] * (size_t)BB * SS + (size_t)row * SS;
    const float* yg = targ + (size_t)row * SS;

    // ---- Load (float4) + Pearson sums (fp32 partials) + min/max, streaming
    //      into LDS (sz = x + i y == FFT1 input, natural order).
    {
        const float4* xg4 = reinterpret_cast<const float4*>(xg);
        const float4* yg4 = reinterpret_cast<const float4*>(yg);
        float sx = 0, sy = 0, sxy = 0, sxx = 0, syy = 0;
        float xmn = 3.4e38f, xmx = -3.4e38f, ymn = 3.4e38f, ymx = -3.4e38f;
        #pragma unroll
        for (int m2 = 0; m2 < 4; ++m2) {
            int idx = t + (m2 << 10);          // float4 index
            float4 a = xg4[idx];
            float4 b = yg4[idx];
            int n0 = idx << 2;
            sz[PD(n0 + 0)] = make_float2(a.x, b.x);
            sz[PD(n0 + 1)] = make_float2(a.y, b.y);
            sz[PD(n0 + 2)] = make_float2(a.z, b.z);
            sz[PD(n0 + 3)] = make_float2(a.w, b.w);
            float av[4] = {a.x, a.y, a.z, a.w};
            float bv[4] = {b.x, b.y, b.z, b.w};
            #pragma unroll
            for (int c = 0; c < 4; ++c) {
                float aa = av[c], bb = bv[c];
                sx += aa; sy += bb;
                sxy += aa * bb;
                sxx += aa * aa;
                syy += bb * bb;
                xmn = fminf(xmn, aa); xmx = fmaxf(xmx, aa);
                ymn = fminf(ymn, bb); ymx = fmaxf(ymx, bb);
            }
        }
        #pragma unroll
        for (int o = 32; o > 0; o >>= 1) {
            sx += __shfl_down(sx, o, 64);  sy += __shfl_down(sy, o, 64);
            sxy += __shfl_down(sxy, o, 64);
            sxx += __shfl_down(sxx, o, 64); syy += __shfl_down(syy, o, 64);
            xmn = fminf(xmn, __shfl_down(xmn, o, 64));
            xmx = fmaxf(xmx, __shfl_down(xmx, o, 64));
            ymn = fminf(ymn, __shfl_down(ymn, o, 64));
            ymx = fmaxf(ymx, __shfl_down(ymx, o, 64));
        }
        if (lane == 0) {
            dpart[w*5+0] = (double)sx; dpart[w*5+1] = (double)sy;
            dpart[w*5+2] = (double)sxy;
            dpart[w*5+3] = (double)sxx; dpart[w*5+4] = (double)syy;
            fpart[w*4+0] = xmn; fpart[w*4+1] = xmx; fpart[w*4+2] = ymn; fpart[w*4+3] = ymx;
        }
    }
    subhist[t] = 0;
    if (t < 576) subhist[1024 + t] = 0;
    __syncthreads();
    if (t == 0) {
        double v0=0,v1=0,v2=0,v3=0,v4=0;
        float b0=fpart[0], b1=fpart[1], b2=fpart[2], b3=fpart[3];
        for (int q = 0; q < 16; ++q) {
            v0 += dpart[q*5]; v1 += dpart[q*5+1]; v2 += dpart[q*5+2];
            v3 += dpart[q*5+3]; v4 += dpart[q*5+4];
            b0 = fminf(b0, fpart[q*4]);   b1 = fmaxf(b1, fpart[q*4+1]);
            b2 = fminf(b2, fpart[q*4+2]); b3 = fmaxf(b3, fpart[q*4+3]);
        }
        double N = (double)SS;
        double num = N * v2 - v0 * v1;
        double den = sqrt((N * v3 - v0 * v0) * (N * v4 - v1 * v1));
        wpear[row] = (float)(1.0 - num / den);
        sbounds[0] = b0; sbounds[1] = 10.0f / (b1 - b0);
        sbounds[2] = b2; sbounds[3] = 10.0f / (b3 - b2);
    }
    __syncthreads();

    // ---- FFT1 stage 1 (Q=2048) with FUSED MI binning
    stage1_mi(sz, t, sbounds[0], sbounds[1], sbounds[2], sbounds[3],
              subhist + w * 100);

    // ---- MI finalize piece A (subhist complete after stage-1 barrier);
    //      ordering of pieces A->B->C->D is provided by the FFT stage
    //      barriers below (FFT stages never touch MI arrays).
    if (t < 100) {
        int s = 0;
        #pragma unroll
        for (int q = 0; q < 16; ++q) s += subhist[t + 100 * q];
        subhist[t] = s;
    }
    stage_dif8<-1, 8>(sz, t);    // Q=256 (barrier orders A -> B)
    if (t < 10) {                // piece B
        int s1 = 0, s2 = 0;
        for (int j = 0; j < 10; ++j) { s1 += subhist[t*10+j]; s2 += subhist[j*10+t]; }
        hxm[t] = (float)s1; hym[t] = (float)s2;
    }
    stage_dif8<-1, 5>(sz, t);    // Q=32 (barrier orders B -> C)
    {                            // piece C
        float term = 0.0f;
        if (t < 100) {
            const float denom = 8388608.0f, eps = 1e-8f;
            float pxy = (float)subhist[t] / denom;
            float px = hxm[t / 10] / denom, py = hym[t % 10] / denom;
            term = pxy * logf((pxy + eps) / (px * py + eps));
        }
        if (t < 128) mterm[t] = (t < 100) ? term : 0.0f;
    }
    stage_dif8<-1, 2>(sz, t);    // Q=4 (barrier orders C -> D)
    if (t == 0) {                // piece D
        const float denom = 8388608.0f, eps = 1e-8f;
        float mi = 0.0f;
        for (int q = 0; q < 100; ++q) mi += mterm[q];
        float hxe = 0.0f, hye = 0.0f;
        for (int q = 0; q < 10; ++q) {
            float px = hxm[q] / denom, py = hym[q] / denom;
            hxe -= px * logf(px + eps);
            hye -= py * logf(py + eps);
        }
        wnmi[row] = mi / (0.5f * (hxe + hye));
    }
    stage_nt4<-1>(sz, t);        // Q=1, twiddle-free

    // ---- Fused unpack: power sums (unwindowed) + phase-correlation C from
    //      the Hann-convolved spectrum (Zw[k] = 0.5Z[k]-0.25(Z[k-1]+Z[k+1]),
    //      exact for the periodic window). Z[k+-1] come from NEIGHBOR LANES
    //      (consecutive lanes hold consecutive k; km mirrors k so Z[km-+1]
    //      is the same neighbor's zb). Lanes 0/63 patch via direct reads.
    //      Reads before barrier; C written to NATURAL slots [0..8192] after.
    {
        double anum = 0.0, aden = 0.0;
        float crv[8], civ[8];
        #pragma unroll 1
        for (int m = 0; m < 8; ++m) {
            int k = t + (m << 10);
            int km = (SS - k) & (SS - 1);
            float2 za = sz[sp(k)];
            float2 zb = sz[sp(km)];
            float ar  = za.x, ai  = za.y;
            float cr0 = zb.x, ci0 = zb.y;
            float xr = 0.5f * (ar + cr0), xi = 0.5f * (ai - ci0);
            float yr = 0.5f * (ai + ci0), yi = 0.5f * (cr0 - ar);
            float xp = xr * xr + xi * xi;
            float tp = yr * yr + yi * yi;
            anum += (double)fabsf(xp - tp);
            aden += (double)tp;
            // neighbors via wave shuffles
            float2 zap, zam, zbp, zbm;
            zap.x = __shfl_down(za.x, 1, 64); zap.y = __shfl_down(za.y, 1, 64);
            zam.x = __shfl_up(za.x, 1, 64);   zam.y = __shfl_up(za.y, 1, 64);
            zbm.x = __shfl_down(zb.x, 1, 64); zbm.y = __shfl_down(zb.y, 1, 64);
            zbp.x = __shfl_up(zb.x, 1, 64);   zbp.y = __shfl_up(zb.y, 1, 64);
            if (lane == 63) {
                zap = sz[sp((k + 1) & (SS - 1))];
                zbm = sz[sp((km - 1) & (SS - 1))];
            }
            if (lane == 0) {
                zam = sz[sp((k - 1) & (SS - 1))];
                zbp = sz[sp((km + 1) & (SS - 1))];
            }
            float zwr = 0.5f * ar  - 0.25f * (zap.x + zam.x);
            float zwi = 0.5f * ai  - 0.25f * (zap.y + zam.y);
            float vwr = 0.5f * cr0 - 0.25f * (zbp.x + zbm.x);
            float vwi = 0.5f * ci0 - 0.25f * (zbp.y + zbm.y);
            float xwr = 0.5f * (zwr + vwr), xwi = 0.5f * (zwi - vwi);
            float ywr = 0.5f * (zwi + vwi), ywi = 0.5f * (vwr - zwr);
            float cr = xwr * ywr + xwi * ywi;
            float ci = xwi * ywr - xwr * ywi;
            float mag = sqrtf(cr * cr + ci * ci);
            crv[m] = cr / mag; civ[m] = ci / mag;
        }
        float c8 = 0.0f;
        if (t == 0) {   // k = 8192 (self-conjugate)
            float2 z0 = sz[sp(8192)];
            float2 zp = sz[sp(8193)];
            float2 zm = sz[sp(8191)];
            float ar = z0.x, ai = z0.y;
            anum += (double)fabsf(ar * ar - ai * ai);
            aden += (double)(ai * ai);
            float zwr = 0.5f * ar - 0.25f * (zp.x + zm.x);
            float zwi = 0.5f * ai - 0.25f * (zp.y + zm.y);
            float pr = zwr * zwi;          // Xw real, Yw real at Nyquist
            c8 = pr / fabsf(pr);
        }
        #pragma unroll
        for (int o = 32; o > 0; o >>= 1) {
            anum += __shfl_down(anum, o, 64);
            aden += __shfl_down(aden, o, 64);
        }
        if (lane == 0) { dpart[w*2] = anum; dpart[w*2+1] = aden; }
        __syncthreads();   // all spectrum reads done; safe to overwrite
        #pragma unroll
        for (int m = 0; m < 8; ++m) {
            int k = t + (m << 10);
            sz[k] = make_float2(crv[m], civ[m]);   // C natural, k in [0,8192)
        }
        if (t == 0) {
            sz[8192] = make_float2(c8, 0.0f);
            double a = 0, b = 0;
            for (int q2_ = 0; q2_ < 16; ++q2_) { a += dpart[q2_*2]; b += dpart[q2_*2+1]; }
            wnum[row] = a; wden[row] = b;
        }
    }
    __syncthreads();

    // ---- 8K inverse: fused B-build+first stage, middle stages, fused last
    inv_first(sz, bz, t);         // B in regs + Q=1024 (barrier inside)
    stage8k_dif8<1,  7>(bz, t);   // Q=128
    stage8k_dif8<1,  4>(bz, t);   // Q=16
    stage8k_dif4<1>(bz, t);       // Q=4
    {
        float bv; int bi;
        inv_last_argmax(bz, t, &bv, &bi);   // Q=1 butterfly + argmax, no store
        #pragma unroll
        for (int o = 32; o > 0; o >>= 1) {
            float v2 = __shfl_down(bv, o, 64);
            int i2 = __shfl_down(bi, o, 64);
            if (v2 > bv || (v2 == bv && i2 < bi)) { bv = v2; bi = i2; }
        }
        if (lane == 0) { svalw[w] = bv; sidxw[w] = bi; }
    }
    __syncthreads();
    if (t == 0) {
        float bv = svalw[0]; int bi = sidxw[0];
        for (int q = 1; q < 16; ++q) {
            if (svalw[q] > bv || (svalw[q] == bv && sidxw[q] < bi)) { bv = svalw[q]; bi = sidxw[q]; }
        }
        wcos[row] = cosf(TPIF * (float)bi / 16384.0f);
    }
}

// ---------------------------------------------------------------------------
// Final combine (reads epoch on-device; graph-safe). Wave-shuffle reductions.
// ---------------------------------------------------------------------------
__global__ __launch_bounds__(512) void k_combine(const float* __restrict__ wpear,
                                                 const float* __restrict__ wcos,
                                                 const double* __restrict__ wnum,
                                                 const double* __restrict__ wden,
                                                 const float* __restrict__ wnmi,
                                                 const int* __restrict__ ep,
                                                 float* __restrict__ out) {
    __shared__ double dp[8 * 5];
    const int tid = threadIdx.x;
    const int w = tid >> 6, lane = tid & 63;
    double v0 = (double)wpear[tid], v1 = (double)wcos[tid];
    double v2 = wnum[tid], v3 = wden[tid], v4 = (double)wnmi[tid];
    #pragma unroll
    for (int o = 32; o > 0; o >>= 1) {
        v0 += __shfl_down(v0, o, 64); v1 += __shfl_down(v1, o, 64);
        v2 += __shfl_down(v2, o, 64); v3 += __shfl_down(v3, o, 64);
        v4 += __shfl_down(v4, o, 64);
    }
    if (lane == 0) {
        dp[w*5+0] = v0; dp[w*5+1] = v1; dp[w*5+2] = v2; dp[w*5+3] = v3; dp[w*5+4] = v4;
    }
    __syncthreads();
    if (tid == 0) {
        double s0=0,s1=0,s2=0,s3=0,s4=0;
        for (int q = 0; q < 8; ++q) {
            s0 += dp[q*5]; s1 += dp[q*5+1]; s2 += dp[q*5+2]; s3 += dp[q*5+3]; s4 += dp[q*5+4];
        }
        int epoch = ep[0];
        double loss = s0 / 512.0;
        if (epoch >= 400) {
            loss += 1.0 - s1 / 512.0;
            loss += s2 / s3;
        }
        if (epoch >= 700) {
            loss += 1.0 - s4 / 512.0;
        }
        out[0] = (float)loss;
    }
}

// ---------------------------------------------------------------------------
extern "C" void kernel_launch(void* const* d_in, const int* in_sizes, int n_in,
                              void* d_out, int out_size, void* d_ws, size_t ws_size,
                              hipStream_t stream) {
    const float* pred = (const float*)d_in[0];   // [2, 512, 16384] f32
    const float* targ = (const float*)d_in[1];   // [512, 16384] f32
    const int* ip = (const int*)d_in[2];         // scalar i
    const int* ep = (const int*)d_in[3];         // scalar epoch
    float* out = (float*)d_out;

    double* wnum = (double*)d_ws;                // [512]
    double* wden = wnum + BB;                    // [512]
    float* wpear = (float*)(wden + BB);          // [512]
    float* wcos = wpear + BB;                    // [512]
    float* wnmi = wcos + BB;                     // [512]

    k_main<<<dim3(BB), dim3(1024), 0, stream>>>(pred, targ, ip, wpear, wcos, wnum, wden, wnmi);
    k_combine<<<dim3(1), dim3(512), 0, stream>>>(wpear, wcos, wnum, wden, wnmi, ep, out);
}